// Round 3
// baseline (845.051 us; speedup 1.0000x reference)
//
#include <hip/hip_runtime.h>
#include <hip/hip_bf16.h>

// Problem constants (fixed shapes from reference):
//   maps: [32, 102, 224, 224] fp32 -> B*A = 3264 slices of 50176 floats
//   weight: [1, 102] fp32, avg_value: scalar fp32
//   out: x_sun [32,102] (3264 f32) then x_son [9,32,1] (288 f32)

#define BA_TOTAL 3264      // 32 * 102
#define HW 50176           // 224 * 224
#define HW_VEC4 12544      // HW / 4
#define ITERS 49           // HW_VEC4 / 256
#define A_DIM 102
#define B_DIM 32

__global__ __launch_bounds__(256) void pool_mean_kernel(
    const float* __restrict__ maps, float* __restrict__ x_sun) {
    const int ba = blockIdx.x;
    const float4* __restrict__ p =
        reinterpret_cast<const float4*>(maps + (size_t)ba * HW);

    float sum = 0.0f;
    // 12544 float4 / 256 threads = 49 iterations, fully coalesced
    for (int i = 0; i < ITERS; ++i) {
        float4 v = p[threadIdx.x + i * 256];
        sum += (v.x + v.y) + (v.z + v.w);
    }

    // wave (64-lane) shuffle reduction
    for (int off = 32; off > 0; off >>= 1)
        sum += __shfl_down(sum, off);

    __shared__ float wsum[4];
    const int lane = threadIdx.x & 63;
    const int wid  = threadIdx.x >> 6;
    if (lane == 0) wsum[wid] = sum;
    __syncthreads();
    if (threadIdx.x == 0) {
        float s = (wsum[0] + wsum[1]) + (wsum[2] + wsum[3]);
        x_sun[ba] = s * (1.0f / (float)HW);
    }
}

__global__ __launch_bounds__(64) void topk_kernel(
    const float* __restrict__ x_sun, const float* __restrict__ weight,
    const float* __restrict__ avg_ptr, float* __restrict__ x_son) {
    const int b = blockIdx.x;
    const int lane = threadIdx.x;

    __shared__ float votes[A_DIM];

    float local = 0.0f;
    for (int a = lane; a < A_DIM; a += 64) {
        float v = x_sun[b * A_DIM + a] * weight[a];
        votes[a] = v;
        local += v;
    }
    // dense sum across the wave
    for (int off = 32; off > 0; off >>= 1)
        local += __shfl_down(local, off);

    __syncthreads();

    if (lane == 0) {
        const float avg = avg_ptr[0];
        unsigned long long used0 = 0ull, used1 = 0ull;
        float csum = 0.0f;
        // 8 passes of serial argmax over 102 elements (tiny; ties -> lowest
        // index first, matching stable argsort of -|vote|)
        for (int k = 0; k < 8; ++k) {
            float best = -1.0f;
            int besti = 0;
            for (int a = 0; a < A_DIM; ++a) {
                bool u = (a < 64) ? ((used0 >> a) & 1ull)
                                  : ((used1 >> (a - 64)) & 1ull);
                float av = fabsf(votes[a]);
                if (!u && av > best) { best = av; besti = a; }
            }
            if (besti < 64) used0 |= 1ull << besti;
            else            used1 |= 1ull << (besti - 64);
            csum += votes[besti];
            x_son[k * B_DIM + b] = csum + avg;
        }
        x_son[8 * B_DIM + b] = local + avg;
    }
}

extern "C" void kernel_launch(void* const* d_in, const int* in_sizes, int n_in,
                              void* d_out, int out_size, void* d_ws, size_t ws_size,
                              hipStream_t stream) {
    const float* maps   = (const float*)d_in[0];
    const float* weight = (const float*)d_in[1];
    const float* avg    = (const float*)d_in[2];
    float* out   = (float*)d_out;
    float* x_sun = out;             // 3264 floats
    float* x_son = out + BA_TOTAL;  // 288 floats

    pool_mean_kernel<<<BA_TOTAL, 256, 0, stream>>>(maps, x_sun);
    topk_kernel<<<B_DIM, 64, 0, stream>>>(x_sun, weight, avg, x_son);
}